// Round 7
// baseline (211.720 us; speedup 1.0000x reference)
//
#include <hip/hip_runtime.h>

#define N_PTS 150000
#define NK 27
#define CIN 128
#define COUT 128
#define BM 256
#define NBLK ((N_PTS + BM - 1) / BM)   // 586

typedef __attribute__((ext_vector_type(8))) short bfrag8;   // 8 bf16
typedef __attribute__((ext_vector_type(4))) float facc4;    // 4 f32

__device__ inline unsigned short f2bf(float f) {
    unsigned u = __builtin_bit_cast(unsigned, f);
    u += 0x7FFFu + ((u >> 16) & 1u);            // RNE
    return (unsigned short)(u >> 16);
}
__device__ inline unsigned pack2(float a, float b) {
    return (unsigned)f2bf(a) | ((unsigned)f2bf(b) << 16);
}
__device__ inline void glds16(const void* g, void* l) {
    __builtin_amdgcn_global_load_lds(
        (const __attribute__((address_space(1))) void*)g,
        (__attribute__((address_space(3))) void*)l, 16, 0, 0);
}
// LDS-visibility barrier: does NOT drain vmcnt (prefetch loads stay in flight)
__device__ inline void lds_barrier() {
    __builtin_amdgcn_sched_barrier(0);
    asm volatile("s_waitcnt lgkmcnt(0)" ::: "memory");
    __builtin_amdgcn_s_barrier();
    __builtin_amdgcn_sched_barrier(0);
}
// full drain barrier (prologue only)
__device__ inline void full_barrier() {
    __builtin_amdgcn_sched_barrier(0);
    asm volatile("s_waitcnt vmcnt(0)" ::: "memory");
    asm volatile("s_waitcnt lgkmcnt(0)" ::: "memory");
    __builtin_amdgcn_s_barrier();
    __builtin_amdgcn_sched_barrier(0);
}

// ---- prep: fp32 data -> bf16, plus one zeroed row at index N_PTS ----
__global__ void cast_data_kernel(const float* __restrict__ in,
                                 unsigned short* __restrict__ out) {
    const int n8_data = N_PTS * (CIN / 8);
    const int n8_all  = (N_PTS + 1) * (CIN / 8);
    int i = blockIdx.x * blockDim.x + threadIdx.x;
    int stride = gridDim.x * blockDim.x;
    for (; i < n8_all; i += stride) {
        uint4 v;
        if (i < n8_data) {
            const float4* p = (const float4*)(in + (size_t)i * 8);
            float4 x = p[0], y = p[1];
            v.x = pack2(x.x, x.y); v.y = pack2(x.z, x.w);
            v.z = pack2(y.x, y.y); v.w = pack2(y.z, y.w);
        } else {
            v.x = v.y = v.z = v.w = 0u;
        }
        *(uint4*)(out + (size_t)i * 8) = v;
    }
}

// ---- prep: W[co][k][ci] -> wkh[k][h][co][bu] bf16 16B units, pre-swizzled bu^(co&7) ----
__global__ void prep_weights_h(const float* __restrict__ w,
                               unsigned short* __restrict__ wkh) {
    int i = blockIdx.x * blockDim.x + threadIdx.x;
    if (i >= NK * 2 * 128 * 8) return;
    int bu = i & 7, co = (i >> 3) & 127, h = (i >> 10) & 1, k = i >> 11;
    int ci = h * 64 + (bu ^ (co & 7)) * 8;
    const float4* src = (const float4*)(w + ((size_t)co * NK + k) * CIN + ci);
    float4 x = src[0], y = src[1];
    uint4 v;
    v.x = pack2(x.x, x.y); v.y = pack2(x.z, x.w);
    v.z = pack2(y.x, y.y); v.w = pack2(y.z, y.w);
    ((uint4*)wkh)[i] = v;
}

// ================= main kernel (v6: T14 reg-staged 2-deep pipeline) =================
// BM=256 x COUT=128, 1024 threads (16 waves), wave = 32 rows x 64 couts.
// 54 phases (27 k x 2 ci-halves, K=64). Phase p: issue reg-loads for p+2,
// MFMA(p), ds_write regs(p+1) -> freed LDS buf, lgkm-barrier (no vmcnt drain).
// Compiler's auto-waitcnt on the reg sets = counted vmcnt(3). All reg names
// static (rule #20). Swizzle discipline unchanged from r6 (rule #21).

#define ISSUE(Q, RA0, RA1, RB)                                             \
  {                                                                        \
    const int q_ = (Q) <= 53 ? (Q) : 53;                                   \
    const int k_ = q_ >> 1;                                                \
    const int hb_ = (q_ & 1) << 7;                                         \
    int iv0 = *(const int*)(ldsI + i0base + k_ * 4);                       \
    int iv1 = *(const int*)(ldsI + i1base + k_ * 4);                       \
    size_t e0 = (r0ok && iv0 >= 0) ? (size_t)iv0 : (size_t)N_PTS;          \
    size_t e1 = (r1ok && iv1 >= 0) ? (size_t)iv1 : (size_t)N_PTS;          \
    RA0 = *(const uint4*)(dbfB + e0 * 256 + hb_ + aswz0);                  \
    RA1 = *(const uint4*)(dbfB + e1 * 256 + hb_ + aswz1);                  \
    RB  = *(const uint4*)(wkhB + (size_t)q_ * 16384 + bsrc_c);             \
  }

#define DSWRITE(ABUF, BBUF, RA0, RA1, RB)                                  \
  {                                                                        \
    *(uint4*)((ABUF) + adst_lin0) = RA0;                                   \
    *(uint4*)((ABUF) + adst_lin1) = RA1;                                   \
    *(uint4*)((BBUF) + bdst_lin)  = RB;                                    \
  }

#define MFMA_PHASE(ABUF, BBUF)                                                      \
  {                                                                                 \
    __builtin_amdgcn_s_setprio(1);                                                  \
    _Pragma("unroll")                                                               \
    for (int kk = 0; kk < 2; ++kk) {                                                \
      const int sw_ = (((kk * 4 + lk) ^ (lr & 7)) << 4);                            \
      bfrag8 a0 = *(const bfrag8*)((ABUF) + (wrow * 32 + lr) * 128 + sw_);          \
      bfrag8 a1 = *(const bfrag8*)((ABUF) + (wrow * 32 + 16 + lr) * 128 + sw_);     \
      _Pragma("unroll")                                                             \
      for (int ct = 0; ct < 4; ++ct) {                                              \
        bfrag8 b = *(const bfrag8*)((BBUF) + (h * 64 + ct * 16 + lr) * 128 + sw_);  \
        acc[0][ct] = __builtin_amdgcn_mfma_f32_16x16x32_bf16(a0, b, acc[0][ct],     \
                                                             0, 0, 0);              \
        acc[1][ct] = __builtin_amdgcn_mfma_f32_16x16x32_bf16(a1, b, acc[1][ct],     \
                                                             0, 0, 0);              \
      }                                                                             \
    }                                                                               \
    __builtin_amdgcn_s_setprio(0);                                                  \
  }

__global__ __launch_bounds__(1024, 4)
void octconv_v6(const unsigned short* __restrict__ dbf,   // [N_PTS+1][128] bf16
                const unsigned short* __restrict__ wkh,   // [27][2][128][8u] preswz
                const int* __restrict__ nbr,
                float* __restrict__ out) {
    __shared__ __align__(1024) unsigned char lds[98304 + 27648];  // A 64K | B 32K | idx 27K

    const int t = threadIdx.x;
    const int w = t >> 6, l = t & 63;
    const int lr = l & 15, lk = l >> 4;
    const int h = w & 1, wrow = w >> 1;
    const int m0 = blockIdx.x * BM;

    const int lu    = l & 7;
    const int slot0 = w * 16 + (l >> 3);
    const int slot1 = slot0 + 8;
    const bool r0ok = (m0 + slot0) < N_PTS;
    const bool r1ok = (m0 + slot1) < N_PTS;
    const int aswz0 = (lu ^ (slot0 & 7)) << 4;
    const int aswz1 = (lu ^ (slot1 & 7)) << 4;
    const int bco   = w * 8 + (l >> 3);
    const int bsrc_c = ((bco * 8 + (l & 7)) << 4);   // LINEAR: source pre-swizzled
    const int i0base = slot0 * 108;
    const int i1base = slot1 * 108;

    const char* dbfB = (const char*)dbf;
    const char* wkhB = (const char*)wkh;
    char* ldsA0 = (char*)lds;
    char* ldsA1 = (char*)lds + 32768;
    char* ldsB0 = (char*)lds + 65536;
    char* ldsB1 = (char*)lds + 81920;
    char* ldsI  = (char*)lds + 98304;

    const int adst_lin0 = (w * 128 + l) * 16;        // A slot rows, linear dest
    const int adst_lin1 = (w * 128 + 64 + l) * 16;
    const int bdst_lin  = t * 16;

    facc4 acc[2][4];
    const facc4 fz = {0.f, 0.f, 0.f, 0.f};
#pragma unroll
    for (int a = 0; a < 2; ++a)
#pragma unroll
        for (int b = 0; b < 4; ++b) acc[a][b] = fz;

    // ---- prologue 1: idx slab via glds (guarded at tail block) ----
    {
        const char* nsrc = (const char*)nbr + (size_t)m0 * 108;
        const int rows_valid = (N_PTS - m0) < BM ? (N_PTS - m0) : BM;
        const int nlimit = rows_valid * 108;
        int o1 = t * 16;
        if (o1 < nlimit) glds16(nsrc + o1, ldsI + o1);
        int o2 = 16384 + t * 16;
        if (t < 704 && o2 < nlimit) glds16(nsrc + o2, ldsI + o2);
    }
    full_barrier();

    // ---- prologue 2: load phases 0,1 to regs; write phase 0 to buf0 ----
    uint4 sa0_0, sa1_0, sb_0;      // set S0 (even phases)
    uint4 sa0_1, sa1_1, sb_1;      // set S1 (odd phases)
    ISSUE(0, sa0_0, sa1_0, sb_0)
    ISSUE(1, sa0_1, sa1_1, sb_1)
    DSWRITE(ldsA0, ldsB0, sa0_0, sa1_0, sb_0)
    lds_barrier();

    // ---- 27 k-iterations x 2 phases ----
#pragma unroll 1
    for (int kp = 0; kp < NK; ++kp) {
        // even phase q=2kp: compute buf0; S0 free -> load q+2; write S1 (q+1) -> buf1
        if (kp < NK - 1) ISSUE(2 * kp + 2, sa0_0, sa1_0, sb_0)
        MFMA_PHASE(ldsA0, ldsB0)
        DSWRITE(ldsA1, ldsB1, sa0_1, sa1_1, sb_1)
        lds_barrier();
        // odd phase q=2kp+1: compute buf1; S1 free -> load q+2; write S0 -> buf0
        if (kp < NK - 1) ISSUE(2 * kp + 3, sa0_1, sa1_1, sb_1)
        MFMA_PHASE(ldsA1, ldsB1)
        DSWRITE(ldsA0, ldsB0, sa0_0, sa1_0, sb_0)
        lds_barrier();
    }

    // ---- epilogue: C/D col=lane&15, row=(lane>>4)*4+reg ----
#pragma unroll
    for (int rt = 0; rt < 2; ++rt) {
        const int r0 = m0 + wrow * 32 + rt * 16 + lk * 4;
#pragma unroll
        for (int ct = 0; ct < 4; ++ct) {
#pragma unroll
            for (int r = 0; r < 4; ++r) {
                int row = r0 + r;
                if (row < N_PTS)
                    out[(size_t)row * COUT + h * 64 + ct * 16 + lr] = acc[rt][ct][r];
            }
        }
    }
}

// ---- emergency fallback ----
__global__ void naive_kernel(const float* __restrict__ data, const float* __restrict__ wgt,
                             const int* __restrict__ nbr, float* __restrict__ out) {
    int mm = blockIdx.x;
    int co = threadIdx.x;
    if (mm >= N_PTS) return;
    float acc = 0.f;
    for (int k = 0; k < NK; ++k) {
        int idx = nbr[mm * NK + k];
        if (idx < 0) continue;
        const float* d  = data + (size_t)idx * CIN;
        const float* wp = wgt + ((size_t)co * NK + k) * CIN;
        for (int ci = 0; ci < CIN; ++ci) acc += d[ci] * wp[ci];
    }
    out[(size_t)mm * COUT + co] = acc;
}

extern "C" void kernel_launch(void* const* d_in, const int* in_sizes, int n_in,
                              void* d_out, int out_size, void* d_ws, size_t ws_size,
                              hipStream_t stream) {
    const float* data = (const float*)d_in[0];
    const float* wgt  = (const float*)d_in[1];
    const int*   nbr  = (const int*)d_in[2];
    float*       out  = (float*)d_out;

    const size_t wk_bytes  = (size_t)NK * 2 * 128 * 8 * 16;    // 884,736
    const size_t dbf_bytes = (size_t)(N_PTS + 1) * CIN * 2;    // 38,400,256

    if (ws_size < wk_bytes + dbf_bytes) {
        naive_kernel<<<N_PTS, COUT, 0, stream>>>(data, wgt, nbr, out);
        return;
    }
    unsigned short* wkh = (unsigned short*)d_ws;
    unsigned short* dbf = (unsigned short*)((char*)d_ws + wk_bytes);

    prep_weights_h<<<(NK * 2 * 128 * 8 + 255) / 256, 256, 0, stream>>>(wgt, wkh);
    cast_data_kernel<<<2048, 256, 0, stream>>>(data, dbf);

    octconv_v6<<<NBLK, 1024, 0, stream>>>(dbf, wkh, nbr, out);
}